// Round 1
// baseline (336.619 us; speedup 1.0000x reference)
//
#include <hip/hip_runtime.h>

// GaussianVoxel fused single-kernel writer, v3: unconditional-zero-stream variant.
// Output: 4 levels [16,17,zr,64,64] f32, zr in {1,2,4,64}, concatenated flat.
// Z_COEFFS=(1,1,1,13): g0..g2 are [1,13,13], g3 is [13,13,13]; PATCH=13, PAD=6.
// 316 MB of mostly zeros -> pure write-bandwidth problem.
//
// v3 change vs v2 (R0 theory): the 16 KB/block store stream is now IDENTICAL
// to the runtime fill kernel for ALL blocks — 4 unconditional nontemporal
// zero stores that do not depend on the coords load. The 4352 blocks whose
// slice intersects the (b,j) patch then drain (vmcnt(0) + __syncthreads, the
// compiler-guaranteed order point) and overwrite only the <=13x13 patch
// footprint (<=169 scalar stores). This removes (a) the coords-load latency
// gating every block's first store and (b) the per-float4 predicated-gather
// path that 22.5% of the bytes previously flowed through.
//
// Timing note (R2 post-mortem, prior session): dur_us includes ~200 us of
// harness 0xAA poison fill (1.266 GB @ 6.35 TB/s) + ~50 us fixed overhead;
// our controllable part is the 316 MB write (floor ~50 us @ 6.35 TB/s).
// Pre-commitment: if this lands within ±1.5 us of 319.5, the kernel was
// already at fill rate -> ROOFLINE.

#define PAD 6
#define PATCH 13
#define PP 169        // 13*13

typedef float f32x4 __attribute__((ext_vector_type(4)));

__global__ __launch_bounds__(256)
void GaussianVoxel_fused(const float* __restrict__ coords,
                         const float* __restrict__ g0,
                         const float* __restrict__ g1,
                         const float* __restrict__ g2,
                         const float* __restrict__ g3,
                         float* __restrict__ out) {
    const int s = blockIdx.x;              // global slice id, 0..19311

    // Decode (level, bj, z) — all wave-uniform.
    int base, zsh;                         // zsh = log2(z_res)
    long long obase;                       // element offset of this level
    const float* g;
    if (s < 272)       { base = 0;    zsh = 0; obase = 0LL;       g = g0; }
    else if (s < 816)  { base = 272;  zsh = 1; obase = 1114112LL; g = g1; }
    else if (s < 1904) { base = 816;  zsh = 2; obase = 3342336LL; g = g2; }
    else               { base = 1904; zsh = 6; obase = 7798784LL; g = g3; }
    const int sid = s - base;
    const int bj  = sid >> zsh;
    const int z   = sid & ((1 << zsh) - 1);
    const int zc   = (zsh == 6) ? 13 : 1;
    const int zpad = (zsh == 6) ? 6  : 0;

    float* __restrict__ oslice = out + obase + (long long)sid * 4096;
    f32x4* __restrict__ o4 = (f32x4*)oslice;

    // Issue the (uniform) coords load early; it is consumed only AFTER the
    // zero stores below, so its latency overlaps the store stream.
    const int xi = (int)coords[bj * 3 + 0];
    const int yi = (int)coords[bj * 3 + 1];
    const int zi = (int)coords[bj * 3 + 2];

    // Phase 1: unconditional streaming zero-fill. 4 coalesced nontemporal
    // 16B stores/thread, no data dependence — same issue pattern as the
    // runtime fill kernel (measured 6.35 TB/s).
    const f32x4 zero = {0.f, 0.f, 0.f, 0.f};
    #pragma unroll
    for (int i = 0; i < 4; ++i)
        __builtin_nontemporal_store(zero, &o4[i * 256 + threadIdx.x]);

    // zidx = ceil(zi * zr / 64) - 1  (exact integer form; zi in [0,63])
    const int zidx = (((zi << zsh) + 63) >> 6) - 1;
    const int gz = z - zidx + zpad;        // patch z-coordinate of this slice

    // Block-uniform test (zi, z, zidx all uniform): 81.6% of blocks retire here.
    if ((unsigned)gz >= (unsigned)zc) return;

    // Phase 2 (intersecting blocks only, ~4352 of 19312): order the patch
    // overwrite after ALL of this block's zero stores. The explicit vmcnt
    // drain + barrier is the documented order point (compiler emits
    // s_waitcnt vmcnt(0) before s_barrier; asm kept for explicitness).
    asm volatile("s_waitcnt vmcnt(0)" ::: "memory");
    __syncthreads();

    const int t = threadIdx.x;
    if (t < PP) {
        const float v = g[gz * PP + t];    // 13x13 plane (gz==0 for L0-2)
        const int py = t / PATCH;
        const int px = t - py * PATCH;
        const int y  = py + yi - PAD;      // inverse of gy = y - yi + PAD
        const int x  = px + xi - PAD;
        if ((unsigned)y < 64u && (unsigned)x < 64u)
            oslice[y * 64 + x] = v;
    }
}

extern "C" void kernel_launch(void* const* d_in, const int* in_sizes, int n_in,
                              void* d_out, int out_size, void* d_ws, size_t ws_size,
                              hipStream_t stream) {
    const float* coords = (const float*)d_in[0];
    const float* g0     = (const float*)d_in[1];
    const float* g1     = (const float*)d_in[2];
    const float* g2     = (const float*)d_in[3];
    const float* g3     = (const float*)d_in[4];
    float* out = (float*)d_out;

    // One block per 64x64 slice: 272*(1+2+4+64) = 19312 slices.
    GaussianVoxel_fused<<<19312, 256, 0, stream>>>(coords, g0, g1, g2, g3, out);
}